// Round 2
// baseline (57.525 us; speedup 1.0000x reference)
//
#include <hip/hip_runtime.h>
#include <math.h>

#define NOUT 64
#define NIN  64
#define HH   32
#define WW   32
#define PADH 34
#define PADW 34

#define NCGRP 4                     // c-groups per block (reduced in LDS)
#define CPER  (NIN / NCGRP)         // 16
#define ROWSPB 2                    // output rows per block
#define TILES  (HH / ROWSPB)        // 16
#define NBLOCKS (NOUT * TILES)      // 1024

// ---------- prep: transpose + zero-pad x[1][32][32][64] -> xt[64][34][34] ----------
__global__ __launch_bounds__(256) void xpose_kernel(const float* __restrict__ x,
                                                    float* __restrict__ xt) {
    int idx = blockIdx.x * 256 + threadIdx.x;
    const int total = NIN * PADH * PADW;
    if (idx >= total) return;
    int jj = idx % PADW;
    int t  = idx / PADW;
    int ii = t % PADH;
    int c  = t / PADH;
    float v = 0.0f;
    if (ii >= 1 && ii <= HH && jj >= 1 && jj <= WW)
        v = x[((ii - 1) * WW + (jj - 1)) * NIN + c];
    xt[idx] = v;
}

// ---------- rational eval: P5(x) / (1 + |x*H3(x)|) ----------
__device__ __forceinline__ void rat_acc(float x, const float* __restrict__ A,
                                        const float* __restrict__ B, float& acc) {
    float p = A[5];
    p = fmaf(p, x, A[4]);
    p = fmaf(p, x, A[3]);
    p = fmaf(p, x, A[2]);
    p = fmaf(p, x, A[1]);
    p = fmaf(p, x, A[0]);
    float q = B[3];
    q = fmaf(q, x, B[2]);
    q = fmaf(q, x, B[1]);
    q = fmaf(q, x, B[0]);
    float den = 1.0f + fabsf(x * q);
    acc = fmaf(p, __builtin_amdgcn_rcpf(den), acc);
}

// ---------- main kernel: one block = (f, 2-row tile); c split 4-way in-block ----------
__global__ __launch_bounds__(256) void kan_main(const float* __restrict__ xt,
                                                const float* __restrict__ wn,
                                                const float* __restrict__ wd,
                                                float* __restrict__ out) {
    __shared__ float red[256];

    // bijective XCD-chunked swizzle: 1024 % 8 == 0, 128 blocks per XCD chunk
    int bid = blockIdx.x;
    int wgid = (bid & 7) * (NBLOCKS / 8) + (bid >> 3);
    int t = wgid & (TILES - 1);
    int f = wgid >> 4;

    int tid = threadIdx.x;
    int g = tid >> 6;          // c-group 0..3
    int p = tid & 63;          // pixel within tile
    int r = p >> 5;            // row 0..1
    int j = p & 31;
    int i = t * ROWSPB + r;
    int c0 = g * CPER;

    const float* xb  = xt + c0 * (PADH * PADW) + i * PADW + j;
    const float* wnb = wn + (f * NIN + c0) * 9 * 6;
    const float* wdb = wd + (f * NIN + c0) * 9 * 4;

    float acc = 0.0f;
    for (int c = 0; c < CPER; ++c) {
        const float* xp = xb + c * (PADH * PADW);
        float xv[9];
#pragma unroll
        for (int a = 0; a < 3; ++a)
#pragma unroll
            for (int b = 0; b < 3; ++b)
                xv[a * 3 + b] = xp[a * PADW + b];
        const float* wnc = wnb + c * 54;
        const float* wdc = wdb + c * 36;
#pragma unroll
        for (int ab = 0; ab < 9; ++ab)
            rat_acc(xv[ab], wnc + ab * 6, wdc + ab * 4, acc);
    }

    red[tid] = acc;
    __syncthreads();
    if (tid < 64) {
        float s = red[tid] + red[tid + 64] + red[tid + 128] + red[tid + 192];
        int rr = tid >> 5;
        int jj = tid & 31;
        out[f * (HH * WW) + (t * ROWSPB + rr) * WW + jj] = s;
    }
}

// ---------- fallback (no workspace): gather NHWC directly, same write-once scheme ----------
__global__ __launch_bounds__(256) void kan_fallback(const float* __restrict__ x,
                                                    const float* __restrict__ wn,
                                                    const float* __restrict__ wd,
                                                    float* __restrict__ out) {
    __shared__ float red[256];
    int bid = blockIdx.x;
    int wgid = (bid & 7) * (NBLOCKS / 8) + (bid >> 3);
    int t = wgid & (TILES - 1);
    int f = wgid >> 4;

    int tid = threadIdx.x;
    int g = tid >> 6;
    int p = tid & 63;
    int r = p >> 5;
    int j = p & 31;
    int i = t * ROWSPB + r;
    int c0 = g * CPER;

    const float* wnb = wn + (f * NIN + c0) * 9 * 6;
    const float* wdb = wd + (f * NIN + c0) * 9 * 4;

    float acc = 0.0f;
    for (int c = 0; c < CPER; ++c) {
        float xv[9];
#pragma unroll
        for (int a = 0; a < 3; ++a)
#pragma unroll
            for (int b = 0; b < 3; ++b) {
                int ii = i + a - 1, jj = j + b - 1;
                bool inb = (ii >= 0) && (ii < HH) && (jj >= 0) && (jj < WW);
                xv[a * 3 + b] = inb ? x[(ii * WW + jj) * NIN + (c0 + c)] : 0.0f;
            }
        const float* wnc = wnb + c * 54;
        const float* wdc = wdb + c * 36;
#pragma unroll
        for (int ab = 0; ab < 9; ++ab)
            rat_acc(xv[ab], wnc + ab * 6, wdc + ab * 4, acc);
    }

    red[tid] = acc;
    __syncthreads();
    if (tid < 64) {
        float s = red[tid] + red[tid + 64] + red[tid + 128] + red[tid + 192];
        int rr = tid >> 5;
        int jj = tid & 31;
        out[f * (HH * WW) + (t * ROWSPB + rr) * WW + jj] = s;
    }
}

extern "C" void kernel_launch(void* const* d_in, const int* in_sizes, int n_in,
                              void* d_out, int out_size, void* d_ws, size_t ws_size,
                              hipStream_t stream) {
    const float* x  = (const float*)d_in[0];
    const float* wn = (const float*)d_in[1];
    const float* wd = (const float*)d_in[2];
    float* out = (float*)d_out;

    const size_t xt_bytes = (size_t)NIN * PADH * PADW * sizeof(float);

    if (ws_size >= xt_bytes) {
        float* xt = (float*)d_ws;
        const int total = NIN * PADH * PADW;  // 73984 = 289 * 256
        xpose_kernel<<<(total + 255) / 256, 256, 0, stream>>>(x, xt);
        kan_main<<<NBLOCKS, 256, 0, stream>>>(xt, wn, wd, out);
    } else {
        kan_fallback<<<NBLOCKS, 256, 0, stream>>>(x, wn, wd, out);
    }
}

// Round 3
// 32.344 us; speedup vs baseline: 1.7785x; 1.7785x over previous
//
#include <hip/hip_runtime.h>
#include <math.h>

#define NOUT 64
#define NIN  64
#define HH   32
#define WW   32
#define PADH 34
#define PADW 34
#define PIXW 8                          // pixels per wave

#define XP_ELEMS  (PADH * PADW * NIN)   // 73984  : xp[ii][jj][c]
#define WTN_ELEMS (NOUT * 9 * 6 * NIN)  // 221184 : wtn[f][ab][n][c]
#define WTD_ELEMS (NOUT * 9 * 4 * NIN)  // 147456 : wtd[f][ab][n][c]

// ---------- prep 1: pad x[1][32][32][64] (NHWC) -> xp[34][34][64] ----------
__global__ __launch_bounds__(256) void xpad_kernel(const float* __restrict__ x,
                                                   float* __restrict__ xp) {
    int idx = blockIdx.x * 256 + threadIdx.x;   // grid sized exactly
    int c  = idx & 63;
    int t  = idx >> 6;
    int jj = t % PADW;
    int ii = t / PADW;
    float v = 0.0f;
    if (ii >= 1 && ii <= HH && jj >= 1 && jj <= WW)
        v = x[((ii - 1) * WW + (jj - 1)) * NIN + c];
    xp[idx] = v;
}

// ---------- prep 2: transpose weights to channel-last ----------
// wn[f][c][ky][kx][n6] -> wtn[f][ab][n][c] ; wd[...n4] -> wtd[f][ab][n][c]
__global__ __launch_bounds__(256) void wtrans_kernel(const float* __restrict__ wn,
                                                     const float* __restrict__ wd,
                                                     float* __restrict__ wtn,
                                                     float* __restrict__ wtd) {
    int idx = blockIdx.x * 256 + threadIdx.x;   // 0 .. WTN+WTD-1 exactly
    if (idx < WTN_ELEMS) {
        int c  = idx & 63;
        int t1 = idx >> 6;
        int n  = t1 % 6;
        int t2 = t1 / 6;
        int ab = t2 % 9;
        int f  = t2 / 9;
        wtn[idx] = wn[((f * NIN + c) * 9 + ab) * 6 + n];
    } else {
        int id2 = idx - WTN_ELEMS;
        int c  = id2 & 63;
        int t1 = id2 >> 6;
        int n  = t1 & 3;
        int t2 = t1 >> 2;
        int ab = t2 % 9;
        int f  = t2 / 9;
        wtd[id2] = wd[((f * NIN + c) * 9 + ab) * 4 + n];
    }
}

// ---------- main: lane=c, wave=(f, row, 8-pixel quarter) ----------
__global__ __launch_bounds__(256) void kan_main(const float* __restrict__ xp,
                                                const float* __restrict__ wtn,
                                                const float* __restrict__ wtd,
                                                float* __restrict__ out) {
    int wv   = blockIdx.x * 4 + (threadIdx.x >> 6);  // 0..8191
    int lane = threadIdx.x & 63;                     // = input channel c
    int f    = wv >> 7;                              // 128 waves per f
    int rem  = wv & 127;
    int i    = rem >> 2;                             // row 0..31
    int j0   = (rem & 3) * PIXW;                     // 0,8,16,24

    float acc[PIXW];
#pragma unroll
    for (int p = 0; p < PIXW; ++p) acc[p] = 0.0f;

    const float* wnb = wtn + f * (9 * 6 * NIN) + lane;
    const float* wdb = wtd + f * (9 * 4 * NIN) + lane;

#pragma unroll
    for (int ab = 0; ab < 9; ++ab) {
        const int a = ab / 3, b = ab % 3;
        // per-lane weight registers for this (f, ab), coalesced loads
        const float a0 = wnb[(ab * 6 + 0) * NIN];
        const float a1 = wnb[(ab * 6 + 1) * NIN];
        const float a2 = wnb[(ab * 6 + 2) * NIN];
        const float a3 = wnb[(ab * 6 + 3) * NIN];
        const float a4 = wnb[(ab * 6 + 4) * NIN];
        const float a5 = wnb[(ab * 6 + 5) * NIN];
        const float b0 = wdb[(ab * 4 + 0) * NIN];
        const float b1 = wdb[(ab * 4 + 1) * NIN];
        const float b2 = wdb[(ab * 4 + 2) * NIN];
        const float b3 = wdb[(ab * 4 + 3) * NIN];

        const float* xb = xp + ((i + a) * PADW + (j0 + b)) * NIN + lane;
#pragma unroll
        for (int p = 0; p < PIXW; ++p) {
            float xv = xb[p * NIN];          // coalesced, immediate offset
            float pn = fmaf(a5, xv, a4);
            pn = fmaf(pn, xv, a3);
            pn = fmaf(pn, xv, a2);
            pn = fmaf(pn, xv, a1);
            pn = fmaf(pn, xv, a0);
            float qn = fmaf(b3, xv, b2);
            qn = fmaf(qn, xv, b1);
            qn = fmaf(qn, xv, b0);
            float den = 1.0f + fabsf(xv * qn);
            acc[p] = fmaf(pn, __builtin_amdgcn_rcpf(den), acc[p]);
        }
    }

    // reduce over lanes (channels); butterfly leaves sum in all lanes
#pragma unroll
    for (int p = 0; p < PIXW; ++p) {
        float s = acc[p];
        s += __shfl_xor(s, 32, 64);
        s += __shfl_xor(s, 16, 64);
        s += __shfl_xor(s, 8, 64);
        s += __shfl_xor(s, 4, 64);
        s += __shfl_xor(s, 2, 64);
        s += __shfl_xor(s, 1, 64);
        if (lane == p) out[f * (HH * WW) + i * WW + j0 + p] = s;
    }
}

// ---------- fallback (tiny ws): round-2 style, write-once ----------
__global__ __launch_bounds__(256) void kan_fallback(const float* __restrict__ x,
                                                    const float* __restrict__ wn,
                                                    const float* __restrict__ wd,
                                                    float* __restrict__ out) {
    __shared__ float red[256];
    int bid = blockIdx.x;
    int t = bid & 15;
    int f = bid >> 4;
    int tid = threadIdx.x;
    int g = tid >> 6;
    int p = tid & 63;
    int r = p >> 5;
    int j = p & 31;
    int i = t * 2 + r;
    int c0 = g * 16;
    const float* wnb = wn + (f * NIN + c0) * 9 * 6;
    const float* wdb = wd + (f * NIN + c0) * 9 * 4;
    float acc = 0.0f;
    for (int c = 0; c < 16; ++c) {
        float xv[9];
#pragma unroll
        for (int a = 0; a < 3; ++a)
#pragma unroll
            for (int b = 0; b < 3; ++b) {
                int ii = i + a - 1, jj = j + b - 1;
                bool inb = (ii >= 0) && (ii < HH) && (jj >= 0) && (jj < WW);
                xv[a * 3 + b] = inb ? x[(ii * WW + jj) * NIN + (c0 + c)] : 0.0f;
            }
        const float* wnc = wnb + c * 54;
        const float* wdc = wdb + c * 36;
#pragma unroll
        for (int ab = 0; ab < 9; ++ab) {
            float xx = xv[ab];
            float pn = fmaf(wnc[ab * 6 + 5], xx, wnc[ab * 6 + 4]);
            pn = fmaf(pn, xx, wnc[ab * 6 + 3]);
            pn = fmaf(pn, xx, wnc[ab * 6 + 2]);
            pn = fmaf(pn, xx, wnc[ab * 6 + 1]);
            pn = fmaf(pn, xx, wnc[ab * 6 + 0]);
            float qn = fmaf(wdc[ab * 4 + 3], xx, wdc[ab * 4 + 2]);
            qn = fmaf(qn, xx, wdc[ab * 4 + 1]);
            qn = fmaf(qn, xx, wdc[ab * 4 + 0]);
            float den = 1.0f + fabsf(xx * qn);
            acc = fmaf(pn, __builtin_amdgcn_rcpf(den), acc);
        }
    }
    red[tid] = acc;
    __syncthreads();
    if (tid < 64) {
        float s = red[tid] + red[tid + 64] + red[tid + 128] + red[tid + 192];
        int rr = tid >> 5;
        int jj = tid & 31;
        out[f * (HH * WW) + (t * 2 + rr) * WW + jj] = s;
    }
}

extern "C" void kernel_launch(void* const* d_in, const int* in_sizes, int n_in,
                              void* d_out, int out_size, void* d_ws, size_t ws_size,
                              hipStream_t stream) {
    const float* x  = (const float*)d_in[0];
    const float* wn = (const float*)d_in[1];
    const float* wd = (const float*)d_in[2];
    float* out = (float*)d_out;

    const size_t need = (size_t)(XP_ELEMS + WTN_ELEMS + WTD_ELEMS) * sizeof(float);

    if (ws_size >= need) {
        float* xp  = (float*)d_ws;
        float* wtn = xp + XP_ELEMS;
        float* wtd = wtn + WTN_ELEMS;

        xpad_kernel<<<XP_ELEMS / 256, 256, 0, stream>>>(x, xp);                    // 289 blocks
        wtrans_kernel<<<(WTN_ELEMS + WTD_ELEMS) / 256, 256, 0, stream>>>(wn, wd, wtn, wtd); // 1440
        kan_main<<<(NOUT * 128) / 4, 256, 0, stream>>>(xp, wtn, wtd, out);         // 2048 blocks
    } else {
        kan_fallback<<<NOUT * 16, 256, 0, stream>>>(x, wn, wd, out);
    }
}

// Round 4
// 27.553 us; speedup vs baseline: 2.0878x; 1.1739x over previous
//
#include <hip/hip_runtime.h>
#include <math.h>

#define NOUT 64
#define NIN  64
#define HH   32
#define WW   32
#define PADH 34
#define PADW 34
#define PIXW 8                           // pixels per wave

#define XP_ELEMS  (PADH * PADW * NIN)    // 73984 : xp[ii][jj][c]
#define NREC      (NOUT * 9 * NIN)       // 36864 weight records
#define WPK_ELEMS (NREC * 12)            // 442368: wpk[f][ab][c][12]

// ---------- fused prep: pad x (NHWC) + pack weights ----------
__global__ __launch_bounds__(256) void prep_kernel(const float* __restrict__ x,
                                                   const float* __restrict__ wn,
                                                   const float* __restrict__ wd,
                                                   float* __restrict__ xp,
                                                   float* __restrict__ wpk) {
    int idx = blockIdx.x * 256 + threadIdx.x;     // grid = (XP_ELEMS + NREC)/256 exact
    if (idx < XP_ELEMS) {
        int c  = idx & 63;
        int t  = idx >> 6;
        int jj = t % PADW;
        int ii = t / PADW;
        float v = 0.0f;
        if (ii >= 1 && ii <= HH && jj >= 1 && jj <= WW)
            v = x[((ii - 1) * WW + (jj - 1)) * NIN + c];
        xp[idx] = v;
    } else {
        int t  = idx - XP_ELEMS;                  // record id
        int c  = t & 63;
        int ab = (t >> 6) % 9;
        int f  = t / (9 * 64);
        const float* sn = wn + ((f * NIN + c) * 9 + ab) * 6;
        const float* sd = wd + ((f * NIN + c) * 9 + ab) * 4;
        float* dst = wpk + ((size_t)((f * 9 + ab) * 64 + c)) * 12;
        dst[0] = sn[0]; dst[1] = sn[1]; dst[2]  = sn[2]; dst[3]  = sn[3];
        dst[4] = sn[4]; dst[5] = sn[5]; dst[6]  = sd[0]; dst[7]  = sd[1];
        dst[8] = sd[2]; dst[9] = sd[3]; dst[10] = 0.0f;  dst[11] = 0.0f;
    }
}

// ---------- main: lane=c, wave=(f, row, 8-pixel quarter), XCD-chunked ----------
__global__ __launch_bounds__(256) void kan_main(const float* __restrict__ xp,
                                                const float* __restrict__ wpk,
                                                float* __restrict__ out) {
    // bijective XCD-chunked swizzle: 2048 blocks, 256 per XCD chunk
    int bid  = blockIdx.x;
    int wgid = (bid & 7) * 256 + (bid >> 3);
    int wv   = wgid * 4 + (threadIdx.x >> 6);     // 0..8191
    int lane = threadIdx.x & 63;                  // = input channel c
    int f    = wv >> 7;                           // 128 waves per f -> 8 f per XCD
    int rem  = wv & 127;
    int i    = rem >> 2;                          // row 0..31
    int j0   = (rem & 3) * PIXW;                  // 0,8,16,24

    float acc[PIXW];
#pragma unroll
    for (int p = 0; p < PIXW; ++p) acc[p] = 0.0f;

    const float4* wr = (const float4*)(wpk + ((size_t)(f * 9) * 64 + lane) * 12);

#pragma unroll 3
    for (int ab = 0; ab < 9; ++ab) {
        const int a = ab / 3, b = ab % 3;
        // 3 vector loads: {a0,a1,a2,a3} {a4,a5,b0,b1} {b2,b3,-,-}
        float4 wA = wr[ab * 192 + 0];             // 64 records * 3 float4
        float4 wB = wr[ab * 192 + 1];
        float4 wC = wr[ab * 192 + 2];

        const float* xb = xp + ((i + a) * PADW + (j0 + b)) * NIN + lane;
#pragma unroll
        for (int p = 0; p < PIXW; ++p) {
            float xv = xb[p * NIN];               // coalesced, imm offset
            float pn = fmaf(wB.y, xv, wB.x);      // a5*x + a4
            pn = fmaf(pn, xv, wA.w);
            pn = fmaf(pn, xv, wA.z);
            pn = fmaf(pn, xv, wA.y);
            pn = fmaf(pn, xv, wA.x);
            float qn = fmaf(wC.y, xv, wC.x);      // b3*x + b2
            qn = fmaf(qn, xv, wB.w);
            qn = fmaf(qn, xv, wB.z);
            float den = 1.0f + fabsf(xv * qn);
            acc[p] = fmaf(pn, __builtin_amdgcn_rcpf(den), acc[p]);
        }
    }

    // reduce over lanes (channels)
#pragma unroll
    for (int p = 0; p < PIXW; ++p) {
        float s = acc[p];
        s += __shfl_xor(s, 32, 64);
        s += __shfl_xor(s, 16, 64);
        s += __shfl_xor(s, 8, 64);
        s += __shfl_xor(s, 4, 64);
        s += __shfl_xor(s, 2, 64);
        s += __shfl_xor(s, 1, 64);
        if (lane == p) out[f * (HH * WW) + i * WW + j0 + p] = s;
    }
}

// ---------- fallback (tiny ws): direct NHWC gather, write-once ----------
__global__ __launch_bounds__(256) void kan_fallback(const float* __restrict__ x,
                                                    const float* __restrict__ wn,
                                                    const float* __restrict__ wd,
                                                    float* __restrict__ out) {
    __shared__ float red[256];
    int bid = blockIdx.x;
    int t = bid & 15;
    int f = bid >> 4;
    int tid = threadIdx.x;
    int g = tid >> 6;
    int p = tid & 63;
    int r = p >> 5;
    int j = p & 31;
    int i = t * 2 + r;
    int c0 = g * 16;
    const float* wnb = wn + (f * NIN + c0) * 9 * 6;
    const float* wdb = wd + (f * NIN + c0) * 9 * 4;
    float acc = 0.0f;
    for (int c = 0; c < 16; ++c) {
        float xv[9];
#pragma unroll
        for (int a = 0; a < 3; ++a)
#pragma unroll
            for (int b = 0; b < 3; ++b) {
                int ii = i + a - 1, jj = j + b - 1;
                bool inb = (ii >= 0) && (ii < HH) && (jj >= 0) && (jj < WW);
                xv[a * 3 + b] = inb ? x[(ii * WW + jj) * NIN + (c0 + c)] : 0.0f;
            }
        const float* wnc = wnb + c * 54;
        const float* wdc = wdb + c * 36;
#pragma unroll
        for (int ab = 0; ab < 9; ++ab) {
            float xx = xv[ab];
            float pn = fmaf(wnc[ab * 6 + 5], xx, wnc[ab * 6 + 4]);
            pn = fmaf(pn, xx, wnc[ab * 6 + 3]);
            pn = fmaf(pn, xx, wnc[ab * 6 + 2]);
            pn = fmaf(pn, xx, wnc[ab * 6 + 1]);
            pn = fmaf(pn, xx, wnc[ab * 6 + 0]);
            float qn = fmaf(wdc[ab * 4 + 3], xx, wdc[ab * 4 + 2]);
            qn = fmaf(qn, xx, wdc[ab * 4 + 1]);
            qn = fmaf(qn, xx, wdc[ab * 4 + 0]);
            float den = 1.0f + fabsf(xx * qn);
            acc = fmaf(pn, __builtin_amdgcn_rcpf(den), acc);
        }
    }
    red[tid] = acc;
    __syncthreads();
    if (tid < 64) {
        float s = red[tid] + red[tid + 64] + red[tid + 128] + red[tid + 192];
        int rr = tid >> 5;
        int jj = tid & 31;
        out[f * (HH * WW) + (t * 2 + rr) * WW + jj] = s;
    }
}

extern "C" void kernel_launch(void* const* d_in, const int* in_sizes, int n_in,
                              void* d_out, int out_size, void* d_ws, size_t ws_size,
                              hipStream_t stream) {
    const float* x  = (const float*)d_in[0];
    const float* wn = (const float*)d_in[1];
    const float* wd = (const float*)d_in[2];
    float* out = (float*)d_out;

    const size_t need = (size_t)(XP_ELEMS + WPK_ELEMS) * sizeof(float);

    if (ws_size >= need) {
        float* xp  = (float*)d_ws;
        float* wpk = xp + XP_ELEMS;
        const int prep_total = XP_ELEMS + NREC;   // 110848 = 433 * 256
        prep_kernel<<<prep_total / 256, 256, 0, stream>>>(x, wn, wd, xp, wpk);
        kan_main<<<2048, 256, 0, stream>>>(xp, wpk, out);
    } else {
        kan_fallback<<<NOUT * 16, 256, 0, stream>>>(x, wn, wd, out);
    }
}